// Round 4
// baseline (291.402 us; speedup 1.0000x reference)
//
#include <hip/hip_runtime.h>
#include <hip/hip_bf16.h>
#include <math.h>

#define B_  16
#define C_  64
#define H_  128
#define W_  128
#define HW_ (H_ * W_)
#define K9C (9 * C_)   // 576
#define TW  130        // transposed buffer spatial dim (128 + 2 halo)
#define PSTR 72        // LDS pixel stride in ushorts (64 ch + 8 pad; 144 B, 16-B aligned)

typedef float f32x4 __attribute__((ext_vector_type(4)));
typedef __bf16 bf16x8 __attribute__((ext_vector_type(8)));

static __device__ __forceinline__ unsigned short f2us(float f) {
    __bf16 h = (__bf16)f;
    return __builtin_bit_cast(unsigned short, h);
}

// ---------------------------------------------------------------------------
// K1: x (NCHW fp32) -> t (b, y', x', c) bf16 with zeroed 1-px halo border.
// Also emits per-(b,row) channel sums -> y0p[b][c][y] (fused global-avg-pool).
__global__ void k_tr(const float* __restrict__ x, unsigned short* __restrict__ t,
                     float* __restrict__ y0p) {
    int blk = blockIdx.x;
    int b = blk >> 7, y = blk & 127;
    __shared__ unsigned short lds[C_ * TW];
    int tid = threadIdx.x;
    float ps[8];
    #pragma unroll
    for (int k = 0; k < 8; ++k) {
        int i = tid + (k << 8);
        int c = i >> 5, xq = i & 31;
        float4 v = *(const float4*)(x + (((size_t)(b * C_ + c)) << 14) + (y << 7) + (xq << 2));
        unsigned int p0 = f2us(v.x) | ((unsigned int)f2us(v.y) << 16);
        unsigned int p1 = f2us(v.z) | ((unsigned int)f2us(v.w) << 16);
        *(unsigned int*)&lds[c * TW + (xq << 2)]     = p0;
        *(unsigned int*)&lds[c * TW + (xq << 2) + 2] = p1;
        ps[k] = v.x + v.y + v.z + v.w;
    }
    #pragma unroll
    for (int off = 16; off > 0; off >>= 1) {
        #pragma unroll
        for (int k = 0; k < 8; ++k) ps[k] += __shfl_down(ps[k], off, 32);
    }
    if ((tid & 31) == 0) {
        int a = tid >> 5;
        #pragma unroll
        for (int k = 0; k < 8; ++k)
            y0p[((size_t)(b * C_ + a + (k << 3))) * 128 + y] = ps[k];
    }
    __syncthreads();
    size_t rowbase = ((size_t)(b * TW + y + 1)) * TW * C_;
    for (int j = tid; j < 128 * 16; j += 256) {
        int px = j >> 4, g = j & 15;
        unsigned short a0 = lds[(4 * g + 0) * TW + px];
        unsigned short a1 = lds[(4 * g + 1) * TW + px];
        unsigned short a2 = lds[(4 * g + 2) * TW + px];
        unsigned short a3 = lds[(4 * g + 3) * TW + px];
        uint2 wv;
        wv.x = a0 | ((unsigned int)a1 << 16);
        wv.y = a2 | ((unsigned int)a3 << 16);
        *(uint2*)(t + rowbase + (size_t)(px + 1) * C_ + (g << 2)) = wv;
    }
    if (tid < 16) {
        int px = (tid < 8) ? 0 : (TW - 1);
        int ch = tid & 7;
        uint4 z = {0, 0, 0, 0};
        *(uint4*)(t + rowbase + (size_t)px * C_ + ch * 8) = z;
    }
    if (y == 0) {
        size_t base = (size_t)b * TW * TW * C_;
        uint4 z = {0, 0, 0, 0};
        for (int i = tid; i < TW * C_ / 8; i += 256)
            *(uint4*)(t + base + (size_t)i * 8) = z;
    }
    if (y == 127) {
        size_t base = ((size_t)(b * TW + TW - 1)) * TW * C_;
        uint4 z = {0, 0, 0, 0};
        for (int i = tid; i < TW * C_ / 8; i += 256)
            *(uint4*)(t + base + (size_t)i * 8) = z;
    }
}

// ---------------------------------------------------------------------------
// K2: reduce y0p -> mean, FC1+relu, FC2+sigmoid -> sgm[b][576]
__global__ void k_fc(const float* __restrict__ y0p,
                     const float* __restrict__ fc_w1,
                     const float* __restrict__ fc_w2,
                     float* __restrict__ sgm) {
    int b = blockIdx.x, t = threadIdx.x;
    __shared__ float red[256];
    __shared__ float sy0[C_];
    __shared__ float sh[4];
    int c = t & 63, part = t >> 6;
    float s = 0.f;
    const float* p = y0p + ((size_t)(b * C_ + c)) * 128 + part * 32;
    for (int yy = 0; yy < 32; ++yy) s += p[yy];
    red[t] = s;
    __syncthreads();
    if (t < C_) {
        float tot = red[t] + red[t + 64] + red[t + 128] + red[t + 192];
        sy0[t] = tot * (1.0f / (float)HW_);
    }
    __syncthreads();
    if (t < 4) {
        float a = 0.f;
        for (int cc = 0; cc < C_; ++cc) a = fmaf(fc_w1[t * C_ + cc], sy0[cc], a);
        sh[t] = fmaxf(a, 0.f);
    }
    __syncthreads();
    for (int i = t; i < K9C; i += 256) {
        float a = 0.f;
        #pragma unroll
        for (int j = 0; j < 4; ++j) a = fmaf(fc_w2[i * 4 + j], sh[j], a);
        sgm[b * K9C + i] = 1.f / (1.f + expf(-a));
    }
}

// ---------------------------------------------------------------------------
// K3: build w_t[b][tap][o][c] = bf16(weight[o][c][tap]*sgm[b][c*9+tap]);
// block 144 additionally builds w1t[tap][o][c] from se_w1.
__global__ void k_wt(const float* __restrict__ weight,
                     const float* __restrict__ sgm,
                     unsigned short* __restrict__ w_t,
                     const float* __restrict__ se_w1,
                     unsigned short* __restrict__ w1t) {
    int blk = blockIdx.x;
    int t = threadIdx.x;
    if (blk == 144) {
        for (int i = t; i < 9 * 16 * 64; i += 256) {
            int tap = i >> 10, o = (i >> 6) & 15, c = i & 63;
            w1t[i] = f2us(se_w1[(o * C_ + c) * 9 + tap]);
        }
        return;
    }
    int b = blk / 9, tap = blk - b * 9;
    __shared__ float lsy[K9C];
    for (int i = t; i < K9C; i += 256) lsy[i] = sgm[b * K9C + i];
    __syncthreads();
    unsigned short* wb = w_t + ((size_t)b * 9 + tap) * 4096;
    #pragma unroll
    for (int k = 0; k < 16; ++k) {
        int i = t + (k << 8);
        int o = i >> 6, c = i & 63;
        wb[i] = f2us(weight[(o * C_ + c) * 9 + tap] * lsy[c * 9 + tap]);
    }
}

// ---------------------------------------------------------------------------
// K4: SE conv1 via MFMA. 32x8 tile, 2 row-phases of 6 staged rows. -> mid NHWC
__global__ void __launch_bounds__(256, 4)
k_se1(const unsigned short* __restrict__ t, const unsigned short* __restrict__ w1t,
      unsigned short* __restrict__ mid) {
    int blk = blockIdx.x;
    int b = blk >> 6, tile = blk & 63;
    int ty0 = (tile >> 2) << 3, tx0 = (tile & 3) << 5;
    int tid = threadIdx.x, lane = tid & 63, wave = tid >> 6;
    int n = lane & 15, q = lane >> 4, qc = q << 3;
    __shared__ __align__(16) unsigned short xt[6 * 34 * PSTR];
    #pragma unroll
    for (int p = 0; p < 2; ++p) {
        if (p) __syncthreads();
        const unsigned short* tb = t + ((size_t)(b * TW) + ty0 + 4 * p) * (TW * C_) + (size_t)tx0 * C_;
        for (int k = 0; k < 7; ++k) {
            int i = tid + (k << 8);
            if (i < 1632) {
                int pl = i >> 3, ch8 = (i & 7) << 3;
                int row = pl / 34, col = pl - row * 34;
                uint4 v = *(const uint4*)(tb + ((size_t)row * TW + col) * C_ + ch8);
                *(uint4*)&xt[(row * 34 + col) * PSTR + ch8] = v;
            }
        }
        __syncthreads();
        f32x4 acc[2] = {};
        #pragma unroll
        for (int kh = 0; kh < 2; ++kh) {
            const unsigned short* wg = w1t + (kh << 5) + qc;
            uint4 afn = *(const uint4*)(wg + (n << 6));
            #pragma unroll
            for (int tap = 0; tap < 9; ++tap) {
                uint4 afc = afn;
                if (tap < 8) afn = *(const uint4*)(wg + ((tap + 1) << 10) + (n << 6));
                int ki = tap / 3, kj = tap - ki * 3;
                int lr = wave + ki;
                #pragma unroll
                for (int nt = 0; nt < 2; ++nt) {
                    bf16x8 bf = *(const bf16x8*)&xt[(lr * 34 + (nt << 4) + n + kj) * PSTR + (kh << 5) + qc];
                    acc[nt] = __builtin_amdgcn_mfma_f32_16x16x32_bf16(
                        __builtin_bit_cast(bf16x8, afc), bf, acc[nt], 0, 0, 0);
                }
            }
        }
        int y = ty0 + 4 * p + wave;
        #pragma unroll
        for (int nt = 0; nt < 2; ++nt) {
            int xx = tx0 + (nt << 4) + n;
            uint2 wv;
            float v0 = fmaxf(acc[nt][0], 0.f), v1 = fmaxf(acc[nt][1], 0.f);
            float v2 = fmaxf(acc[nt][2], 0.f), v3 = fmaxf(acc[nt][3], 0.f);
            wv.x = f2us(v0) | ((unsigned int)f2us(v1) << 16);
            wv.y = f2us(v2) | ((unsigned int)f2us(v3) << 16);
            *(uint2*)(mid + (((size_t)(b << 14) + (y << 7) + xx) << 4) + (q << 2)) = wv;
        }
    }
}

// ---------------------------------------------------------------------------
// K5: SE conv2 (16->1) + sigmoid -> A[b,HW], LDS-staged. Block = 2 rows x 128 px.
#define MSTR 24   // LDS px stride ushorts (16 ch + 8 pad; 48 B, 16-B aligned)
__global__ void k_se2(const unsigned short* __restrict__ mid,
                      const float* __restrict__ se_w2,
                      float* __restrict__ A) {
    int blk = blockIdx.x;
    int b = blk >> 6, y0 = (blk & 63) << 1;
    int tid = threadIdx.x;
    int rr = tid >> 7, px = tid & 127;
    __shared__ __align__(16) unsigned short ms[4 * 130 * MSTR];
    __shared__ float w2[144];
    if (tid < 144) w2[tid] = se_w2[tid];
    #pragma unroll
    for (int k = 0; k < 4; ++k) {
        int i = tid + (k << 8);
        int sr = i >> 8, rem = i & 255, p2 = rem >> 1, half = rem & 1;
        int gy = y0 - 1 + sr;
        uint4 v = {0, 0, 0, 0};
        if (gy >= 0 && gy < 128)
            v = *(const uint4*)(mid + (((size_t)(b << 14) + (gy << 7) + p2) << 4) + (half << 3));
        *(uint4*)&ms[(sr * 130 + p2 + 1) * MSTR + (half << 3)] = v;
    }
    if (tid < 16) {
        int sr = tid & 3, side = (tid >> 2) & 1, half = tid >> 3;
        int pidx = side ? 129 : 0;
        uint4 z = {0, 0, 0, 0};
        *(uint4*)&ms[(sr * 130 + pidx) * MSTR + (half << 3)] = z;
    }
    __syncthreads();
    float s = 0.f;
    #pragma unroll
    for (int ki = 0; ki < 3; ++ki) {
        #pragma unroll
        for (int kj = 0; kj < 3; ++kj) {
            int base = ((rr + ki) * 130 + px + kj) * MSTR;
            bf16x8 v0 = *(const bf16x8*)&ms[base];
            bf16x8 v1 = *(const bf16x8*)&ms[base + 8];
            #pragma unroll
            for (int e = 0; e < 8; ++e) {
                s = fmaf((float)v0[e], w2[e * 9 + ki * 3 + kj], s);
                s = fmaf((float)v1[e], w2[(e + 8) * 9 + ki * 3 + kj], s);
            }
        }
    }
    A[(b << 14) + ((y0 + rr) << 7) + px] = 1.f / (1.f + expf(-s));
}

// ---------------------------------------------------------------------------
// K6: main conv via MFMA. 32x8 tile, 2 row-phases (6 rows x 34 px x 64 ch LDS),
// A-frag double-buffer prefetch, full-cache-line reads and writes.
__global__ void __launch_bounds__(256, 4)
k_main(const unsigned short* __restrict__ t, const unsigned short* __restrict__ w_t,
       const float* __restrict__ A, float* __restrict__ out) {
    int blk = blockIdx.x;
    int b = blk >> 6, tile = blk & 63;
    int ty0 = (tile >> 2) << 3, tx0 = (tile & 3) << 5;
    int tid = threadIdx.x, lane = tid & 63, wave = tid >> 6;
    int n = lane & 15, q = lane >> 4, qc = q << 3;
    __shared__ __align__(16) unsigned short xt[6 * 34 * PSTR];   // 28.7 KB
    const unsigned short* wb = w_t + (size_t)b * 9 * 4096;
    #pragma unroll
    for (int p = 0; p < 2; ++p) {
        if (p) __syncthreads();
        const unsigned short* tb = t + ((size_t)(b * TW) + ty0 + 4 * p) * (TW * C_) + (size_t)tx0 * C_;
        for (int k = 0; k < 7; ++k) {
            int i = tid + (k << 8);
            if (i < 1632) {
                int pl = i >> 3, ch8 = (i & 7) << 3;
                int row = pl / 34, col = pl - row * 34;
                uint4 v = *(const uint4*)(tb + ((size_t)row * TW + col) * C_ + ch8);
                *(uint4*)&xt[(row * 34 + col) * PSTR + ch8] = v;
            }
        }
        __syncthreads();
        f32x4 acc[4][2] = {};   // [m-tile][n-tile]
        #pragma unroll
        for (int kh = 0; kh < 2; ++kh) {
            const unsigned short* wg = wb + (kh << 5) + qc;
            uint4 afn[4];
            #pragma unroll
            for (int mt = 0; mt < 4; ++mt)
                afn[mt] = *(const uint4*)(wg + ((mt * 16 + n) << 6));
            #pragma unroll
            for (int tap = 0; tap < 9; ++tap) {
                uint4 afc[4];
                #pragma unroll
                for (int mt = 0; mt < 4; ++mt) afc[mt] = afn[mt];
                if (tap < 8) {
                    #pragma unroll
                    for (int mt = 0; mt < 4; ++mt)
                        afn[mt] = *(const uint4*)(wg + ((tap + 1) << 12) + ((mt * 16 + n) << 6));
                }
                int ki = tap / 3, kj = tap - ki * 3;
                int lr = wave + ki;                      // 0..5
                #pragma unroll
                for (int nt = 0; nt < 2; ++nt) {
                    bf16x8 bf = *(const bf16x8*)&xt[(lr * 34 + (nt << 4) + n + kj) * PSTR + (kh << 5) + qc];
                    #pragma unroll
                    for (int mt = 0; mt < 4; ++mt)
                        acc[mt][nt] = __builtin_amdgcn_mfma_f32_16x16x32_bf16(
                            __builtin_bit_cast(bf16x8, afc[mt]), bf, acc[mt][nt], 0, 0, 0);
                }
            }
        }
        // epilogue: 1 output row per wave this phase; full 128-B line per (o,y)
        int y = ty0 + 4 * p + wave;
        #pragma unroll
        for (int nt = 0; nt < 2; ++nt) {
            int xx = tx0 + (nt << 4) + n;
            float a = A[(b << 14) + (y << 7) + xx];
            #pragma unroll
            for (int mt = 0; mt < 4; ++mt) {
                #pragma unroll
                for (int r = 0; r < 4; ++r) {
                    int o = (mt << 4) + (q << 2) + r;
                    out[(((size_t)(b * C_ + o)) << 14) + (y << 7) + xx] = acc[mt][nt][r] * a;
                }
            }
        }
    }
}

// ---------------------------------------------------------------------------
extern "C" void kernel_launch(void* const* d_in, const int* in_sizes, int n_in,
                              void* d_out, int out_size, void* d_ws, size_t ws_size,
                              hipStream_t stream) {
    const float* x      = (const float*)d_in[0];
    const float* weight = (const float*)d_in[1];
    const float* se_w1  = (const float*)d_in[2];
    const float* se_w2  = (const float*)d_in[3];
    const float* fc_w1  = (const float*)d_in[4];
    const float* fc_w2  = (const float*)d_in[5];
    float* out = (float*)d_out;

    char* ws = (char*)d_ws;
    float* y0p           = (float*)ws;             ws += (size_t)B_ * C_ * 128 * 4;
    float* sgm           = (float*)ws;             ws += (size_t)B_ * K9C * 4;
    float* A             = (float*)ws;             ws += (size_t)B_ * HW_ * 4;
    unsigned short* t    = (unsigned short*)ws;    ws += (size_t)B_ * TW * TW * C_ * 2 + 4096;
    unsigned short* w_t  = (unsigned short*)ws;    ws += (size_t)B_ * 9 * C_ * C_ * 2;
    unsigned short* w1t  = (unsigned short*)ws;    ws += 9 * 16 * C_ * 2 + 2048;
    unsigned short* mid  = (unsigned short*)ws;

    k_tr  <<<B_ * H_, 256, 0, stream>>>(x, t, y0p);
    k_fc  <<<B_, 256, 0, stream>>>(y0p, fc_w1, fc_w2, sgm);
    k_wt  <<<B_ * 9 + 1, 256, 0, stream>>>(weight, sgm, w_t, se_w1, w1t);
    k_se1 <<<B_ * 64, 256, 0, stream>>>(t, w1t, mid);
    k_se2 <<<B_ * 64, 256, 0, stream>>>(mid, se_w2, A);
    k_main<<<B_ * 64, 256, 0, stream>>>(t, w_t, A, out);
}